// Round 4
// baseline (121.266 us; speedup 1.0000x reference)
//
#include <hip/hip_runtime.h>

// Problem constants
#define NPATCH 196
#define M_ROWS 12544          // 64*196 = 196 blocks * 64 rows
#define KDIM 768              // 3*16*16
#define DDIM 384              // EMBED
#define HW (224*224)

typedef __attribute__((ext_vector_type(8))) short s16x8;
typedef __attribute__((ext_vector_type(4))) float f32x4;
typedef __attribute__((ext_vector_type(4))) unsigned short u16x4;

__device__ __forceinline__ unsigned short f2bf(float f) {
    unsigned int u = __float_as_uint(f);
    u += 0x7fff + ((u >> 16) & 1);   // round-to-nearest-even
    return (unsigned short)(u >> 16);
}

__device__ __forceinline__ void load_lds16(const void* g, void* l) {
    __builtin_amdgcn_global_load_lds(
        (const __attribute__((address_space(1))) unsigned int*)g,
        (__attribute__((address_space(3))) unsigned int*)l, 16, 0, 0);
}

// ---------------- kernel 1: weights fp32 -> bf16 (384x768 row-major = B^T) ---
__global__ __launch_bounds__(256) void wcast_kernel(const float* __restrict__ w,
                                                    unsigned short* __restrict__ W) {
    int t = blockIdx.x * 256 + threadIdx.x;   // 73728 float4s
    float4 v = ((const float4*)w)[t];
    u16x4 o = { f2bf(v.x), f2bf(v.y), f2bf(v.z), f2bf(v.w) };
    *(u16x4*)(W + t * 4) = o;
}

// ------- kernel 2: fused entropy + im2col-in-LDS + bf16 MFMA GEMM + bias + LN
// 196 blocks x 384 threads (6 waves). Block owns 64 rows (patches) x all 384
// cols. Phase 0: one wave per patch computes the grayscale histogram entropy
// and caches the patch's img base offset in LDS. K-loop: per 64-wide K-tile,
// stage B via global_load_lds (bf16 W, XOR-swizzled source) and stage A
// directly from img (fp32 float4 -> bf16 -> swizzled ds_write_b64) -- the 12
// K-tiles partition the pixels, so each pixel is loaded once here (L2/L3-hot
// from phase 0). A is never materialized in global memory.
__global__ __launch_bounds__(384) void fused_kernel(const float* __restrict__ img,
                                                    const unsigned short* __restrict__ Bt,
                                                    const float* __restrict__ bias,
                                                    const float* __restrict__ gamma,
                                                    const float* __restrict__ beta,
                                                    float* __restrict__ C,
                                                    float* __restrict__ ent) {
    __shared__ __align__(16) unsigned short As[64 * 64];    // 8 KB, per K-tile
    __shared__ __align__(16) unsigned short Bs[384 * 64];   // 48 KB, per K-tile
    __shared__ int hist[6][32];
    __shared__ int pbase[64];
    __shared__ float sred[64], sred2[64], smean[64], srstd[64];

    const int tid  = threadIdx.x;
    const int lane = tid & 63;
    const int w    = tid >> 6;                // wave 0..5
    const int quad = lane >> 4;
    const int cl   = lane & 15;
    const int rowBase = blockIdx.x * 64;

    if (tid < 64) { sred[tid] = 0.0f; sred2[tid] = 0.0f; }

    // ---- phase 0: entropy, one wave per patch (11 wave-iters) ----
    for (int it = 0; it < 11; ++it) {
        int lp = w + it * 6;                  // wave-uniform
        if (lp >= 64) break;
        if (lane < 32) hist[w][lane] = 0;     // in-wave DS pipe is in-order
        int p = rowBase + lp;
        int b = p / NPATCH;
        int n = p - b * NPATCH;
        int ph = n / 14, pw2 = n - ph * 14;
        int base = b * (3 * HW) + (ph * 16) * 224 + pw2 * 16;
        if (lane == 0) pbase[lp] = base;
        const float* q0 = img + base + (lane >> 2) * 224 + (lane & 3) * 4;
        float4 v0 = *(const float4*)(q0);
        float4 v1 = *(const float4*)(q0 + HW);
        float4 v2 = *(const float4*)(q0 + 2 * HW);
        float g[4] = { (v0.x + v1.x + v2.x) * (1.0f / 3.0f),
                       (v0.y + v1.y + v2.y) * (1.0f / 3.0f),
                       (v0.z + v1.z + v2.z) * (1.0f / 3.0f),
                       (v0.w + v1.w + v2.w) * (1.0f / 3.0f) };
#pragma unroll
        for (int j = 0; j < 4; ++j) {
            int bin = (int)(g[j] * 31.0f);
            bin = bin < 0 ? 0 : (bin > 31 ? 31 : bin);
            atomicAdd(&hist[w][bin], 1);
        }
        float t = 0.0f;
        if (lane < 32) {
            float pr = (float)hist[w][lane] * (1.0f / 256.0f);
            t = -pr * log2f(pr + 1e-10f);
        }
#pragma unroll
        for (int off = 32; off; off >>= 1) t += __shfl_xor(t, off);
        if (lane == 0) ent[p] = t * (1.0f / 5.0f);
    }
    __syncthreads();                          // pbase ready for all waves

    f32x4 acc[4][4] = {};

    for (int kt = 0; kt < KDIM; kt += 64) {
        // ---- stage B tile (384x64): 3072 16B-chunks, 8 per thread ----
#pragma unroll
        for (int i = 0; i < 8; ++i) {
            int c = i * 384 + tid;
            int n = c >> 3, kss = c & 7;
            load_lds16(Bt + (size_t)n * KDIM + kt + ((kss ^ (n & 7)) * 8),
                       (unsigned short*)Bs + c * 8);
        }
        // ---- stage A tile (64 rows x 64 k) straight from img ----
        // k-slice = channel cch, patch-rows pr0..pr0+3; 1024 float4 loads.
        const int cch = kt >> 8;
        const int pr0 = (kt & 255) >> 4;
#pragma unroll
        for (int j = 0; j < 3; ++j) {
            int f = j * 384 + tid;
            if (j == 2 && tid >= 256) break;  // wave-uniform tail
            int m = f >> 4, q = f & 15;
            int pr = q >> 2, cg = q & 3;
            float4 v = *(const float4*)(img + pbase[m] + cch * HW + (pr0 + pr) * 224 + cg * 4);
            int kl = pr * 16 + cg * 4;        // k within tile, 0..63
            int kc = kl >> 3, half = (kl >> 2) & 1;
            int slot = kc ^ (m & 7);
            u16x4 o = { f2bf(v.x), f2bf(v.y), f2bf(v.z), f2bf(v.w) };
            *(u16x4*)((char*)As + m * 128 + slot * 16 + half * 8) = o;
        }
        __syncthreads();
        // ---- MFMA: 2 k-steps x 4x4 per wave ----
#pragma unroll
        for (int ks = 0; ks < 2; ++ks) {
            const int sw = (ks * 4 + quad) ^ (cl & 7);
            s16x8 a_frag[4], b_frag[4];
#pragma unroll
            for (int i = 0; i < 4; ++i) {
                a_frag[i] = *(const s16x8*)(As + (i * 16 + cl) * 64 + sw * 8);
                b_frag[i] = *(const s16x8*)(Bs + (w * 64 + i * 16 + cl) * 64 + sw * 8);
            }
#pragma unroll
            for (int i = 0; i < 4; ++i)
#pragma unroll
                for (int j = 0; j < 4; ++j)
                    acc[i][j] = __builtin_amdgcn_mfma_f32_16x16x32_bf16(
                        a_frag[i], b_frag[j], acc[i][j], 0, 0, 0);
        }
        __syncthreads();
    }

    // ---- epilogue: bias + LayerNorm(384) + write (validated in R3) ----
    float bv[4], gv[4], btv[4];
#pragma unroll
    for (int j = 0; j < 4; ++j) {
        int col = w * 64 + j * 16 + cl;
        bv[j] = bias[col]; gv[j] = gamma[col]; btv[j] = beta[col];
    }
#pragma unroll
    for (int i = 0; i < 4; ++i) {
#pragma unroll
        for (int r = 0; r < 4; ++r) {
            float s1 = 0.0f, s2 = 0.0f;
#pragma unroll
            for (int j = 0; j < 4; ++j) {
                float v = acc[i][j][r] + bv[j];
                s1 += v; s2 += v * v;
            }
#pragma unroll
            for (int off = 1; off < 16; off <<= 1) {
                s1 += __shfl_xor(s1, off);
                s2 += __shfl_xor(s2, off);
            }
            if (cl == 0) {
                int row = i * 16 + quad * 4 + r;
                atomicAdd(&sred[row], s1);
                atomicAdd(&sred2[row], s2);
            }
        }
    }
    __syncthreads();
    if (tid < 64) {
        float mu  = sred[tid] * (1.0f / (float)DDIM);
        float var = sred2[tid] * (1.0f / (float)DDIM) - mu * mu;
        smean[tid] = mu;
        srstd[tid] = rsqrtf(var + 1e-5f);
    }
    __syncthreads();

#pragma unroll
    for (int i = 0; i < 4; ++i) {
#pragma unroll
        for (int r = 0; r < 4; ++r) {
            int row = i * 16 + quad * 4 + r;
            float mu = smean[row], rs = srstd[row];
            float* crow = C + (size_t)(rowBase + row) * DDIM;
#pragma unroll
            for (int j = 0; j < 4; ++j)
                crow[w * 64 + j * 16 + cl] = (acc[i][j][r] + bv[j] - mu) * rs * gv[j] + btv[j];
        }
    }
}

extern "C" void kernel_launch(void* const* d_in, const int* in_sizes, int n_in,
                              void* d_out, int out_size, void* d_ws, size_t ws_size,
                              hipStream_t stream) {
    const float* img = (const float*)d_in[0];
    const float* pw  = (const float*)d_in[1];
    const float* pb  = (const float*)d_in[2];
    const float* gam = (const float*)d_in[3];
    const float* bet = (const float*)d_in[4];
    float* out = (float*)d_out;

    unsigned short* Wbf = (unsigned short*)d_ws;            // 384*768*2 = 589824 B
    float* ent = out + (size_t)M_ROWS * DDIM;               // entropy after x

    hipLaunchKernelGGL(wcast_kernel, dim3(288), dim3(256), 0, stream, pw, Wbf);
    hipLaunchKernelGGL(fused_kernel, dim3(196), dim3(384), 0, stream,
                       img, Wbf, pb, gam, bet, out, ent);
}

// Round 5
// 121.090 us; speedup vs baseline: 1.0015x; 1.0015x over previous
//
#include <hip/hip_runtime.h>

// Problem constants
#define NPATCH 196
#define M_ROWS 12544          // 64*196
#define KDIM 768              // 3*16*16
#define DDIM 384              // EMBED
#define HW (224*224)

typedef __attribute__((ext_vector_type(8))) short s16x8;
typedef __attribute__((ext_vector_type(4))) float f32x4;
typedef __attribute__((ext_vector_type(4))) unsigned short u16x4;

__device__ __forceinline__ unsigned short f2bf(float f) {
    unsigned int u = __float_as_uint(f);
    u += 0x7fff + ((u >> 16) & 1);   // round-to-nearest-even
    return (unsigned short)(u >> 16);
}

__device__ __forceinline__ void load_lds16(const void* g, void* l) {
    __builtin_amdgcn_global_load_lds(
        (const __attribute__((address_space(1))) unsigned int*)g,
        (__attribute__((address_space(3))) unsigned int*)l, 16, 0, 0);
}

// ------- kernel 1: fused im2col(bf16) + patch entropy + weight cast ----------
// blocks [0,3136): one wave per patch -> bf16 A row + grayscale histogram.
// blocks [3136,3424): weight fp32->bf16 cast (384x768 row-major = B^T).
__global__ __launch_bounds__(256) void patch_kernel(const float* __restrict__ img,
                                                    const float* __restrict__ w,
                                                    unsigned short* __restrict__ A,
                                                    unsigned short* __restrict__ W,
                                                    float* __restrict__ ent) {
    if (blockIdx.x >= 3136) {                 // ---- weight cast part ----
        int t = (blockIdx.x - 3136) * 256 + threadIdx.x;   // 73728 float4s
        float4 v = ((const float4*)w)[t];
        u16x4 o = { f2bf(v.x), f2bf(v.y), f2bf(v.z), f2bf(v.w) };
        *(u16x4*)(W + t * 4) = o;
        return;
    }
    __shared__ int hist[4][32];
    const int lane = threadIdx.x & 63;
    const int wave = threadIdx.x >> 6;
    const int p = blockIdx.x * 4 + wave;      // 0..12543 == A row index
    const int b = p / NPATCH;
    const int n = p - b * NPATCH;
    const int ph = n / 14, pw = n - ph * 14;

    if (lane < 32) hist[wave][lane] = 0;
    __syncthreads();

    const int r = lane >> 2;                  // pixel row in patch 0..15
    const int cc = (lane & 3) * 4;            // pixel col 0,4,8,12
    const float* base = img + (size_t)b * (3 * HW) + (ph * 16 + r) * 224 + pw * 16 + cc;

    float4 v0 = *(const float4*)(base);
    float4 v1 = *(const float4*)(base + HW);
    float4 v2 = *(const float4*)(base + 2 * HW);

    unsigned short* arow = A + (size_t)p * KDIM;
    u16x4 o0 = { f2bf(v0.x), f2bf(v0.y), f2bf(v0.z), f2bf(v0.w) };
    u16x4 o1 = { f2bf(v1.x), f2bf(v1.y), f2bf(v1.z), f2bf(v1.w) };
    u16x4 o2 = { f2bf(v2.x), f2bf(v2.y), f2bf(v2.z), f2bf(v2.w) };
    *(u16x4*)(arow + 0 * 256 + lane * 4) = o0;
    *(u16x4*)(arow + 1 * 256 + lane * 4) = o1;
    *(u16x4*)(arow + 2 * 256 + lane * 4) = o2;

    float g[4] = { (v0.x + v1.x + v2.x) * (1.0f / 3.0f),
                   (v0.y + v1.y + v2.y) * (1.0f / 3.0f),
                   (v0.z + v1.z + v2.z) * (1.0f / 3.0f),
                   (v0.w + v1.w + v2.w) * (1.0f / 3.0f) };
#pragma unroll
    for (int j = 0; j < 4; ++j) {
        int bin = (int)(g[j] * 31.0f);
        bin = bin < 0 ? 0 : (bin > 31 ? 31 : bin);
        atomicAdd(&hist[wave][bin], 1);
    }
    __syncthreads();

    float t = 0.0f;
    if (lane < 32) {
        float pr = (float)hist[wave][lane] * (1.0f / 256.0f);
        t = -pr * log2f(pr + 1e-10f);
    }
#pragma unroll
    for (int off = 32; off; off >>= 1) t += __shfl_xor(t, off);
    if (lane == 0) ent[p] = t * (1.0f / 5.0f);   // / log2(32)
}

// ------- kernel 2: bf16 MFMA GEMM, 1 wave per 64x64 tile, XOR-swizzled LDS --
// Grid (6,196) = 1176 blocks -> ~4.6 independent waves/CU: barriers are
// wave-local and staging drains are hidden by TLP across blocks.
// LDS slot ks of row r holds global chunk ks^(r&7); fragment read of global
// chunk kc uses slot kc^(cl&7) -> uniform 2 lanes/bank (free, m136).
__global__ __launch_bounds__(64) void gemm_kernel(const unsigned short* __restrict__ A,
                                                  const unsigned short* __restrict__ Bt,
                                                  const float* __restrict__ bias,
                                                  float* __restrict__ C) {
    __shared__ __align__(16) unsigned short As[64 * 64];
    __shared__ __align__(16) unsigned short Bs[64 * 64];
    const int lane = threadIdx.x;
    const int quad = lane >> 4;
    const int cl   = lane & 15;
    const int rowBase = blockIdx.y * 64;
    const int colBase = blockIdx.x * 64;

    f32x4 acc[4][4] = {};

    for (int kt = 0; kt < KDIM; kt += 64) {
#pragma unroll
        for (int i = 0; i < 8; ++i) {
            int f = i * 64 + lane;            // 0..511
            int r = f >> 3, kss = f & 7;
            int ksg = (kss ^ (r & 7)) * 8;
            load_lds16(A  + (size_t)(rowBase + r) * KDIM + kt + ksg, (unsigned short*)As + f * 8);
            load_lds16(Bt + (size_t)(colBase + r) * KDIM + kt + ksg, (unsigned short*)Bs + f * 8);
        }
        __syncthreads();
#pragma unroll
        for (int ks = 0; ks < 2; ++ks) {
            const int sw = (ks * 4 + quad) ^ (cl & 7);
            s16x8 a_frag[4], b_frag[4];
#pragma unroll
            for (int i = 0; i < 4; ++i) {
                a_frag[i] = *(const s16x8*)(As + (i * 16 + cl) * 64 + sw * 8);
                b_frag[i] = *(const s16x8*)(Bs + (i * 16 + cl) * 64 + sw * 8);
            }
#pragma unroll
            for (int i = 0; i < 4; ++i)
#pragma unroll
                for (int j = 0; j < 4; ++j)
                    acc[i][j] = __builtin_amdgcn_mfma_f32_16x16x32_bf16(
                        a_frag[i], b_frag[j], acc[i][j], 0, 0, 0);
        }
        __syncthreads();
    }

    // epilogue: C/D layout col = lane&15, row = (lane>>4)*4 + reg
#pragma unroll
    for (int j = 0; j < 4; ++j) {
        int col = colBase + j * 16 + cl;
        float bv = bias[col];
#pragma unroll
        for (int i = 0; i < 4; ++i) {
            int row0 = rowBase + i * 16 + quad * 4;
#pragma unroll
            for (int r = 0; r < 4; ++r)
                C[(size_t)(row0 + r) * DDIM + col] = acc[i][j][r] + bv;
        }
    }
}

// ---------------- kernel 3: LayerNorm (in-place on d_out x-region) -----------
__global__ __launch_bounds__(256) void ln_kernel(float* __restrict__ X,
                                                 const float* __restrict__ gamma,
                                                 const float* __restrict__ beta) {
    __shared__ float sg[DDIM], sb[DDIM];
    for (int i = threadIdx.x; i < DDIM; i += 256) { sg[i] = gamma[i]; sb[i] = beta[i]; }
    __syncthreads();
    const int lane = threadIdx.x & 63;
    const int wave = threadIdx.x >> 6;
    const int row = blockIdx.x * 4 + wave;
    float* x = X + (size_t)row * DDIM + lane * 6;

    float2 p0 = *(float2*)(x);
    float2 p1 = *(float2*)(x + 2);
    float2 p2 = *(float2*)(x + 4);
    float v[6] = { p0.x, p0.y, p1.x, p1.y, p2.x, p2.y };

    float s = v[0] + v[1] + v[2] + v[3] + v[4] + v[5];
#pragma unroll
    for (int off = 32; off; off >>= 1) s += __shfl_xor(s, off);
    float mean = s * (1.0f / (float)DDIM);

    float d = 0.0f;
#pragma unroll
    for (int j = 0; j < 6; ++j) { float t = v[j] - mean; d += t * t; }
#pragma unroll
    for (int off = 32; off; off >>= 1) d += __shfl_xor(d, off);
    float rstd = 1.0f / sqrtf(d * (1.0f / (float)DDIM) + 1e-5f);

    const float* g = sg + lane * 6;
    const float* b = sb + lane * 6;
#pragma unroll
    for (int j = 0; j < 6; ++j) x[j] = (v[j] - mean) * rstd * g[j] + b[j];
}

extern "C" void kernel_launch(void* const* d_in, const int* in_sizes, int n_in,
                              void* d_out, int out_size, void* d_ws, size_t ws_size,
                              hipStream_t stream) {
    const float* img = (const float*)d_in[0];
    const float* pw  = (const float*)d_in[1];
    const float* pb  = (const float*)d_in[2];
    const float* gam = (const float*)d_in[3];
    const float* bet = (const float*)d_in[4];
    float* out = (float*)d_out;

    unsigned short* Abf = (unsigned short*)d_ws;                       // 12544*768*2 = 19267584 B
    unsigned short* Wbf = (unsigned short*)((char*)d_ws + 19267584);   // 384*768*2  = 589824 B
    float* ent = out + (size_t)M_ROWS * DDIM;                          // entropy after x

    hipLaunchKernelGGL(patch_kernel, dim3(3424),   dim3(256), 0, stream,
                       img, pw, Abf, Wbf, ent);
    hipLaunchKernelGGL(gemm_kernel,  dim3(6, 196), dim3(64),  0, stream,
                       Abf, Wbf, pb, out);
    hipLaunchKernelGGL(ln_kernel,    dim3(3136),   dim3(256), 0, stream,
                       out, gam, bet);
}